// Round 1
// baseline (4124.694 us; speedup 1.0000x reference)
//
#include <hip/hip_runtime.h>
#include <cstddef>

#define N_NODES_  100000
#define N_HEDGES_ 200000
#define E_        1200000
#define G_        512
#define H_        64
#define HE_       35
#define D_        99      // H_+HE_
#define HOUT_     128
#define L_        3

__device__ __forceinline__ float sigm_(float x){ return 1.f/(1.f+__expf(-x)); }
__device__ __forceinline__ float sp_(float x){ return fmaxf(x,0.f)+log1pf(__expf(-fabsf(x))); }

// ---------------- embed: h = x @ We + be  ([N,92]@[92,64]) ----------------
__global__ void k_embed(const float* __restrict__ x, const float* __restrict__ We,
                        const float* __restrict__ be, float* __restrict__ h){
  __shared__ float xs[4][92];
  int sub = threadIdx.x >> 6, f = threadIdx.x & 63;
  int node = blockIdx.x*4 + sub;
  for (int i = threadIdx.x; i < 4*92; i += 256){
    int r = i/92, c = i - r*92;
    int nn = blockIdx.x*4 + r;
    xs[r][c] = (nn < N_NODES_) ? x[(size_t)nn*92 + c] : 0.f;
  }
  __syncthreads();
  if (node >= N_NODES_) return;
  float acc = be[f];
  const float* xr = xs[sub];
  for (int k = 0; k < 92; ++k) acc += xr[k]*We[k*64+f];
  h[(size_t)node*64+f] = acc;
}

// ---------------- per-call counts ----------------
__global__ void k_counts(const int* __restrict__ ni, const int* __restrict__ hi,
                         int* __restrict__ hcnt, int* __restrict__ ndeg){
  int e = blockIdx.x*256 + threadIdx.x;
  if (e >= E_) return;
  atomicAdd(&hcnt[hi[e]], 1);
  atomicAdd(&ndeg[ni[e]], 1);
}
__global__ void k_gcnt(const int* __restrict__ batch, int* __restrict__ gcnt){
  int n = blockIdx.x*256 + threadIdx.x;
  if (n < N_NODES_) atomicAdd(&gcnt[batch[n]], 1);
}

// ---------------- scatter node feats into hedge sums ----------------
__global__ void k_scatter_hedge(const float* __restrict__ h, const int* __restrict__ ni,
                                const int* __restrict__ hi, float* __restrict__ hsum){
  int t = blockIdx.x*256 + threadIdx.x;
  int e = t >> 6; if (e >= E_) return;
  int f = t & 63;
  int n = ni[e], he = hi[e];
  atomicAdd(&hsum[(size_t)he*64+f], h[(size_t)n*64+f]);
}

// ---------------- hedge MLP pre-BN: tf/tc = msg@W + b, accumulate col stats ----------------
__global__ void k_hedge_mlp1(const float* __restrict__ hsum, const int* __restrict__ hcnt,
                             const float* __restrict__ hattr,
                             const float* __restrict__ Wf1, const float* __restrict__ bf1,
                             const float* __restrict__ Wc1, const float* __restrict__ bc1,
                             float* __restrict__ tf, float* __restrict__ tc,
                             float* __restrict__ hstats){
  __shared__ float msg[4][D_];
  __shared__ float s1[70], s2[70];
  for (int i = threadIdx.x; i < 70; i += 256){ s1[i]=0.f; s2[i]=0.f; }
  __syncthreads();
  int lane = threadIdx.x & 63, sub = threadIdx.x >> 6;
  for (int base = blockIdx.x*4; base < N_HEDGES_; base += gridDim.x*4){
    int hh = base + sub;
    if (hh < N_HEDGES_){
      float inv = 1.f / fmaxf((float)hcnt[hh], 1.f);
      msg[sub][lane] = hsum[(size_t)hh*64+lane]*inv;
      if (lane < HE_) msg[sub][64+lane] = hattr[(size_t)hh*HE_+lane];
    }
    __syncthreads();
    if (hh < N_HEDGES_ && lane < HE_){
      float af = bf1[lane], ac = bc1[lane];
      const float* m = msg[sub];
      for (int k = 0; k < D_; ++k){
        float mv = m[k];
        af += mv*Wf1[k*HE_+lane];
        ac += mv*Wc1[k*HE_+lane];
      }
      tf[(size_t)hh*HE_+lane] = af;
      tc[(size_t)hh*HE_+lane] = ac;
      atomicAdd(&s1[lane], af);      atomicAdd(&s2[lane], af*af);
      atomicAdd(&s1[35+lane], ac);   atomicAdd(&s2[35+lane], ac*ac);
    }
    __syncthreads();
  }
  for (int i = threadIdx.x; i < 70; i += 256){
    atomicAdd(&hstats[i], s1[i]);
    atomicAdd(&hstats[70+i], s2[i]);
  }
}

// ---------------- BN finalize (hedge): a,b per column ----------------
__global__ void k_bn_fin_hedge(const float* __restrict__ stats,
                               const float* __restrict__ gf, const float* __restrict__ btf,
                               const float* __restrict__ gc, const float* __restrict__ btc,
                               float* __restrict__ ab, float invN){
  int j = threadIdx.x;
  if (j >= 70) return;
  float m = stats[j]*invN;
  float var = stats[70+j]*invN - m*m;
  float gg = (j < 35) ? gf[j] : gc[j-35];
  float bb = (j < 35) ? btf[j] : btc[j-35];
  float a = gg*rsqrtf(var + 1e-5f);
  ab[j] = a; ab[70+j] = bb - m*a;
}

// ---------------- hedge feats + project to H: heF/heC = hf @ W2_bot + b2 ----------------
__global__ void k_hedge_feats(const float* __restrict__ tf, const float* __restrict__ tc,
                              const float* __restrict__ ab,
                              const float* __restrict__ Wf2, const float* __restrict__ bf2,
                              const float* __restrict__ Wc2, const float* __restrict__ bc2,
                              float* __restrict__ heF, float* __restrict__ heC){
  __shared__ float hf[4][HE_];
  int lane = threadIdx.x & 63, sub = threadIdx.x >> 6;
  int hh = blockIdx.x*4 + sub;
  if (hh < N_HEDGES_ && lane < HE_){
    float zf = ab[lane]*tf[(size_t)hh*HE_+lane] + ab[70+lane];
    float zc = ab[35+lane]*tc[(size_t)hh*HE_+lane] + ab[105+lane];
    hf[sub][lane] = sigm_(zf)*sp_(zc);
  }
  __syncthreads();
  if (hh >= N_HEDGES_) return;
  float aF = bf2[lane], aC = bc2[lane];
  const float* v = hf[sub];
  for (int k = 0; k < HE_; ++k){
    float hv = v[k];
    aF += hv*Wf2[(64+k)*64+lane];
    aC += hv*Wc2[(64+k)*64+lane];
  }
  heF[(size_t)hh*64+lane] = aF;
  heC[(size_t)hh*64+lane] = aC;
}

// ---------------- node projections: nF/nC = h @ W2_top ----------------
__global__ void k_node_lin(const float* __restrict__ h,
                           const float* __restrict__ Wf2, const float* __restrict__ Wc2,
                           float* __restrict__ nF, float* __restrict__ nC){
  __shared__ float hs[4][64];
  int lane = threadIdx.x & 63, sub = threadIdx.x >> 6;
  int node = blockIdx.x*4 + sub;
  hs[sub][lane] = (node < N_NODES_) ? h[(size_t)node*64+lane] : 0.f;
  __syncthreads();
  if (node >= N_NODES_) return;
  float aF = 0.f, aC = 0.f;
  const float* v = hs[sub];
  for (int k = 0; k < 64; ++k){
    float hv = v[k];
    aF += hv*Wf2[k*64+lane];
    aC += hv*Wc2[k*64+lane];
  }
  nF[(size_t)node*64+lane] = aF;
  nC[(size_t)node*64+lane] = aC;
}

// ---------------- edge kernel: gather + gated act + scatter into node sums ----------------
__global__ void k_edge(const float* __restrict__ nF, const float* __restrict__ nC,
                       const float* __restrict__ heF, const float* __restrict__ heC,
                       const int* __restrict__ ni, const int* __restrict__ hi,
                       float* __restrict__ nsum){
  int t = blockIdx.x*256 + threadIdx.x;
  int e = t >> 6; if (e >= E_) return;
  int f = t & 63;
  int n = ni[e], he = hi[e];
  float vF = nF[(size_t)n*64+f] + heF[(size_t)he*64+f];
  float vC = nC[(size_t)n*64+f] + heC[(size_t)he*64+f];
  float o = sigm_(vF)*sp_(vC);
  atomicAdd(&nsum[(size_t)n*64+f], o);
}

// ---------------- node BN stats over mean values ----------------
__global__ void k_node_stats(const float* __restrict__ nsum, const int* __restrict__ ndeg,
                             float* __restrict__ nstats){
  __shared__ float p1[256], p2[256];
  int f = threadIdx.x & 63, r = threadIdx.x >> 6;
  float s = 0.f, q = 0.f;
  int hi_n = blockIdx.x*1024 + 1024; if (hi_n > N_NODES_) hi_n = N_NODES_;
  for (int n = blockIdx.x*1024 + r; n < hi_n; n += 4){
    float v = nsum[(size_t)n*64+f] / fmaxf((float)ndeg[n], 1.f);
    s += v; q += v*v;
  }
  p1[threadIdx.x] = s; p2[threadIdx.x] = q;
  __syncthreads();
  if (r == 0){
    s = p1[f] + p1[64+f] + p1[128+f] + p1[192+f];
    q = p2[f] + p2[64+f] + p2[128+f] + p2[192+f];
    atomicAdd(&nstats[f], s);
    atomicAdd(&nstats[64+f], q);
  }
}

__global__ void k_bn_fin_node(const float* __restrict__ stats, const float* __restrict__ g,
                              const float* __restrict__ bt, float* __restrict__ ab, float invN){
  int j = threadIdx.x;
  if (j >= 64) return;
  float m = stats[j]*invN;
  float var = stats[64+j]*invN - m*m;
  float a = g[j]*rsqrtf(var + 1e-5f);
  ab[j] = a; ab[64+j] = bt[j] - m*a;
}

// ---------------- node update: h' = softplus(BN(mean) + h)  (relu elided: softplus>0) ----------------
__global__ void k_node_update(const float* __restrict__ nsum, const int* __restrict__ ndeg,
                              const float* __restrict__ ab, const float* __restrict__ h,
                              float* __restrict__ hout){
  int t = blockIdx.x*256 + threadIdx.x;
  int n = t >> 6; if (n >= N_NODES_) return;
  int f = t & 63;
  float v = nsum[t] / fmaxf((float)ndeg[n], 1.f);
  float z = ab[f]*v + ab[64+f] + h[t];
  hout[t] = sp_(z);
}

// ---------------- graph mean + head ----------------
__global__ void k_graph_agg(const float* __restrict__ h, const int* __restrict__ batch,
                            float* __restrict__ gsum){
  int t = blockIdx.x*256 + threadIdx.x;
  int n = t >> 6; if (n >= N_NODES_) return;
  int f = t & 63;
  atomicAdd(&gsum[(size_t)batch[n]*64+f], h[t]);
}

__global__ void k_head(const float* __restrict__ gsum, const int* __restrict__ gcnt,
                       const float* __restrict__ Wl2, const float* __restrict__ bl2,
                       const float* __restrict__ Wo, const float* __restrict__ bo,
                       float* __restrict__ out){
  __shared__ float gm[64];
  __shared__ float red[128];
  int g = blockIdx.x, j = threadIdx.x;
  if (j < 64) gm[j] = gsum[(size_t)g*64+j] / fmaxf((float)gcnt[g], 1.f);
  __syncthreads();
  float u = bl2[j];
  for (int f = 0; f < 64; ++f) u += gm[f]*Wl2[f*128+j];
  red[j] = sp_(u)*Wo[j];
  __syncthreads();
  for (int s = 64; s > 0; s >>= 1){
    if (j < s) red[j] += red[j+s];
    __syncthreads();
  }
  if (j == 0) out[g] = red[0] + bo[0];
}

extern "C" void kernel_launch(void* const* d_in, const int* in_sizes, int n_in,
                              void* d_out, int out_size, void* d_ws, size_t ws_size,
                              hipStream_t stream){
  (void)in_sizes; (void)n_in; (void)out_size; (void)ws_size;
  const float* x      = (const float*)d_in[0];
  const int*   ni     = (const int*)d_in[1];          // hyperedge_index row 0
  const int*   hi     = ni + E_;                      // row 1
  const float* hattr  = (const float*)d_in[2];
  const int*   batch  = (const int*)d_in[3];
  const float* We     = (const float*)d_in[4];
  const float* be     = (const float*)d_in[5];
  const float* Wf1    = (const float*)d_in[6];
  const float* bf1    = (const float*)d_in[7];
  const float* Wc1    = (const float*)d_in[8];
  const float* bc1    = (const float*)d_in[9];
  const float* Wf2    = (const float*)d_in[10];
  const float* bf2    = (const float*)d_in[11];
  const float* Wc2    = (const float*)d_in[12];
  const float* bc2    = (const float*)d_in[13];
  const float* bn_f_g = (const float*)d_in[14];
  const float* bn_f_b = (const float*)d_in[15];
  const float* bn_c_g = (const float*)d_in[16];
  const float* bn_c_b = (const float*)d_in[17];
  const float* bn_o_g = (const float*)d_in[18];
  const float* bn_o_b = (const float*)d_in[19];
  const float* Wl2    = (const float*)d_in[20];
  const float* bl2    = (const float*)d_in[21];
  const float* Wo     = (const float*)d_in[22];
  const float* bo     = (const float*)d_in[23];

  float* ws = (float*)d_ws;
  size_t o = 0;
  float* h0   = ws + o; o += (size_t)N_NODES_*H_;
  float* h1   = ws + o; o += (size_t)N_NODES_*H_;
  float* hsum = ws + o; o += (size_t)N_HEDGES_*H_;
  float* nsum = hsum;                                  // alias: live after hsum consumed
  float* nF   = hsum + (size_t)N_NODES_*H_;            // alias: upper half of hsum
  float* tf   = ws + o; o += (size_t)N_HEDGES_*HE_;
  float* nC   = tf;                                    // alias: live after tf consumed
  float* tc   = ws + o; o += (size_t)N_HEDGES_*HE_;
  float* heF  = ws + o; o += (size_t)N_HEDGES_*H_;
  float* heC  = ws + o; o += (size_t)N_HEDGES_*H_;
  float* hstats = ws + o; o += 256;
  float* habs   = ws + o; o += 256;
  float* nstats = ws + o; o += 128;
  float* nabs   = ws + o; o += 128;
  float* gsum   = ws + o; o += (size_t)G_*H_;
  int* hcnt = (int*)(ws + o); o += N_HEDGES_;
  int* ndeg = (int*)(ws + o); o += N_NODES_;
  int* gcnt = (int*)(ws + o); o += G_;

  // per-call count buffers (index-only, reused across layers)
  hipMemsetAsync(hcnt, 0, sizeof(int)*N_HEDGES_, stream);
  hipMemsetAsync(ndeg, 0, sizeof(int)*N_NODES_, stream);
  hipMemsetAsync(gcnt, 0, sizeof(int)*G_, stream);
  hipMemsetAsync(gsum, 0, sizeof(float)*G_*H_, stream);

  k_embed<<<(N_NODES_+3)/4, 256, 0, stream>>>(x, We, be, h0);
  k_counts<<<(E_+255)/256, 256, 0, stream>>>(ni, hi, hcnt, ndeg);
  k_gcnt<<<(N_NODES_+255)/256, 256, 0, stream>>>(batch, gcnt);

  float* hcur = h0;
  float* hnxt = h1;
  for (int l = 0; l < L_; ++l){
    const float* Wf1l = Wf1 + (size_t)l*D_*HE_;
    const float* Wc1l = Wc1 + (size_t)l*D_*HE_;
    const float* Wf2l = Wf2 + (size_t)l*D_*H_;
    const float* Wc2l = Wc2 + (size_t)l*D_*H_;

    hipMemsetAsync(hsum, 0, sizeof(float)*(size_t)N_HEDGES_*H_, stream);
    hipMemsetAsync(hstats, 0, sizeof(float)*140, stream);
    hipMemsetAsync(nstats, 0, sizeof(float)*128, stream);

    k_scatter_hedge<<<E_/4, 256, 0, stream>>>(hcur, ni, hi, hsum);
    k_hedge_mlp1<<<1024, 256, 0, stream>>>(hsum, hcnt, hattr, Wf1l, bf1 + l*HE_,
                                           Wc1l, bc1 + l*HE_, tf, tc, hstats);
    k_bn_fin_hedge<<<1, 128, 0, stream>>>(hstats, bn_f_g + l*HE_, bn_f_b + l*HE_,
                                          bn_c_g + l*HE_, bn_c_b + l*HE_, habs,
                                          1.f/(float)N_HEDGES_);
    k_hedge_feats<<<(N_HEDGES_+3)/4, 256, 0, stream>>>(tf, tc, habs, Wf2l, bf2 + l*H_,
                                                       Wc2l, bc2 + l*H_, heF, heC);
    // hsum fully consumed; zero its lower half as nsum
    hipMemsetAsync(nsum, 0, sizeof(float)*(size_t)N_NODES_*H_, stream);
    k_node_lin<<<(N_NODES_+3)/4, 256, 0, stream>>>(hcur, Wf2l, Wc2l, nF, nC);
    k_edge<<<E_/4, 256, 0, stream>>>(nF, nC, heF, heC, ni, hi, nsum);
    k_node_stats<<<(N_NODES_+1023)/1024, 256, 0, stream>>>(nsum, ndeg, nstats);
    k_bn_fin_node<<<1, 64, 0, stream>>>(nstats, bn_o_g + l*H_, bn_o_b + l*H_, nabs,
                                        1.f/(float)N_NODES_);
    k_node_update<<<(N_NODES_*H_)/256, 256, 0, stream>>>(nsum, ndeg, nabs, hcur, hnxt);
    float* t2 = hcur; hcur = hnxt; hnxt = t2;
  }

  k_graph_agg<<<(N_NODES_*H_)/256, 256, 0, stream>>>(hcur, batch, gsum);
  k_head<<<G_, 128, 0, stream>>>(gsum, gcnt, Wl2, bl2, Wo, bo, (float*)d_out);
}

// Round 2
// 3449.622 us; speedup vs baseline: 1.1957x; 1.1957x over previous
//
#include <hip/hip_runtime.h>
#include <cstddef>

#define N_NODES_  100000
#define N_HEDGES_ 200000
#define E_        1200000
#define G_        512
#define H_        64
#define HE_       35
#define D_        99      // H_+HE_
#define HOUT_     128
#define L_        3

__device__ __forceinline__ float sigm_(float x){ return 1.f/(1.f+__expf(-x)); }
__device__ __forceinline__ float sp_(float x){ return fmaxf(x,0.f)+log1pf(__expf(-fabsf(x))); }

// ---------------- per-call counts ----------------
__global__ void k_counts(const int* __restrict__ ni, const int* __restrict__ hi,
                         int* __restrict__ hcnt, int* __restrict__ ndeg){
  int e = blockIdx.x*256 + threadIdx.x;
  if (e >= E_) return;
  atomicAdd(&hcnt[hi[e]], 1);
  atomicAdd(&ndeg[ni[e]], 1);
}
__global__ void k_gcnt(const int* __restrict__ batch, int* __restrict__ gcnt){
  int n = blockIdx.x*256 + threadIdx.x;
  if (n < N_NODES_) atomicAdd(&gcnt[batch[n]], 1);
}
__global__ void k_inv(const int* __restrict__ hcnt, const int* __restrict__ ndeg,
                      float* __restrict__ hinv, float* __restrict__ ninv){
  int i = blockIdx.x*256 + threadIdx.x;
  if (i < N_HEDGES_) hinv[i] = 1.f/fmaxf((float)hcnt[i], 1.f);
  if (i < N_NODES_)  ninv[i] = 1.f/fmaxf((float)ndeg[i], 1.f);
}

// ---------------- embed: h = x @ We + be  ([100K,92]@[92,64]) ----------------
// Tiled GEMM: KP=100, N=64, NC=4, 64-row tiles, persistent blocks.
__global__ void k_embed(const float* __restrict__ x, const float* __restrict__ We,
                        const float* __restrict__ be, float* __restrict__ h){
  __shared__ __align__(16) float As[64*100];
  __shared__ __align__(16) float Ws[64*100];
  int tid = threadIdx.x;
  for (int idx = tid; idx < 64*100; idx += 256){
    int c = idx/100, k = idx - c*100;
    Ws[idx] = (k < 92) ? We[k*64 + c] : 0.f;
  }
  int rt = tid & 15, ct = tid >> 4;
  float bias[4];
  #pragma unroll
  for (int j = 0; j < 4; ++j) bias[j] = be[ct*4 + ((j + ct) & 3)];
  const int ntiles = (N_NODES_ + 63)/64;
  for (int tile = blockIdx.x; tile < ntiles; tile += gridDim.x){
    int rbase = tile*64;
    __syncthreads();
    for (int idx = tid; idx < 64*100; idx += 256){
      int r = idx/100, k = idx - r*100;
      int rg = rbase + r;
      As[idx] = (rg < N_NODES_ && k < 92) ? x[(size_t)rg*92 + k] : 0.f;
    }
    __syncthreads();
    float acc[4][4] = {};
    for (int kc = 0; kc < 25; ++kc){
      float4 av[4], wv[4];
      #pragma unroll
      for (int i = 0; i < 4; ++i) av[i] = *(const float4*)&As[(rt + 16*i)*100 + kc*4];
      #pragma unroll
      for (int j = 0; j < 4; ++j) wv[j] = *(const float4*)&Ws[(ct*4 + ((j + ct) & 3))*100 + kc*4];
      #pragma unroll
      for (int i = 0; i < 4; ++i)
        #pragma unroll
        for (int j = 0; j < 4; ++j)
          acc[i][j] += av[i].x*wv[j].x + av[i].y*wv[j].y + av[i].z*wv[j].z + av[i].w*wv[j].w;
    }
    #pragma unroll
    for (int i = 0; i < 4; ++i){
      int r = rbase + rt + 16*i;
      if (r < N_NODES_){
        #pragma unroll
        for (int j = 0; j < 4; ++j){
          int c = ct*4 + ((j + ct) & 3);
          h[(size_t)r*64 + c] = acc[i][j] + bias[j];
        }
      }
    }
  }
}

// ---------------- scatter node feats into hedge sums ----------------
__global__ void k_scatter_hedge(const float* __restrict__ h, const int* __restrict__ ni,
                                const int* __restrict__ hi, float* __restrict__ hsum){
  int t = blockIdx.x*256 + threadIdx.x;
  int e = t >> 6; if (e >= E_) return;
  int f = t & 63;
  int n = ni[e], he = hi[e];
  atomicAdd(&hsum[(size_t)he*64+f], h[(size_t)n*64+f]);
}

// ---------------- hedge MLP pre-BN: tfc = [msg@Wf1+bf1 | msg@Wc1+bc1], col stats ----------------
// GEMM [200K x 99] @ [99 x 70]; KP=100, Npad=80, NC=5.
__global__ void k_hedge_mlp1(const float* __restrict__ hsum, const float* __restrict__ hinv,
                             const float* __restrict__ hattr,
                             const float* __restrict__ Wf1, const float* __restrict__ bf1,
                             const float* __restrict__ Wc1, const float* __restrict__ bc1,
                             float* __restrict__ tfc, float* __restrict__ hstats){
  __shared__ __align__(16) float As[64*100];
  __shared__ __align__(16) float Ws[80*100];
  __shared__ float sstat[160];
  int tid = threadIdx.x;
  for (int idx = tid; idx < 80*100; idx += 256){
    int c = idx/100, k = idx - c*100;
    float w = 0.f;
    if (k < 99){
      if (c < 35)      w = Wf1[k*35 + c];
      else if (c < 70) w = Wc1[k*35 + (c - 35)];
    }
    Ws[idx] = w;
  }
  for (int idx = tid; idx < 160; idx += 256) sstat[idx] = 0.f;
  int rt = tid & 15, ct = tid >> 4;
  float bias[5];
  #pragma unroll
  for (int j = 0; j < 5; ++j){
    int c = ct*5 + j;
    bias[j] = (c < 35) ? bf1[c] : (c < 70 ? bc1[c - 35] : 0.f);
  }
  for (int tile = blockIdx.x; tile < N_HEDGES_/64; tile += gridDim.x){
    int rbase = tile*64;
    __syncthreads();
    for (int idx = tid; idx < 64*100; idx += 256){
      int r = idx/100, k = idx - r*100;
      int rg = rbase + r;
      float v = 0.f;
      if (k < 64)      v = hsum[(size_t)rg*64 + k] * hinv[rg];
      else if (k < 99) v = hattr[(size_t)rg*35 + (k - 64)];
      As[idx] = v;
    }
    __syncthreads();
    float acc[4][5] = {};
    for (int kc = 0; kc < 25; ++kc){
      float4 av[4], wv[5];
      #pragma unroll
      for (int i = 0; i < 4; ++i) av[i] = *(const float4*)&As[(rt + 16*i)*100 + kc*4];
      #pragma unroll
      for (int j = 0; j < 5; ++j) wv[j] = *(const float4*)&Ws[(ct*5 + j)*100 + kc*4];
      #pragma unroll
      for (int i = 0; i < 4; ++i)
        #pragma unroll
        for (int j = 0; j < 5; ++j)
          acc[i][j] += av[i].x*wv[j].x + av[i].y*wv[j].y + av[i].z*wv[j].z + av[i].w*wv[j].w;
    }
    #pragma unroll
    for (int j = 0; j < 5; ++j){
      int c = ct*5 + j;
      if (c < 70){
        float s = 0.f, q = 0.f;
        #pragma unroll
        for (int i = 0; i < 4; ++i){
          float v = acc[i][j] + bias[j];
          int r = rbase + rt + 16*i;
          tfc[(size_t)r*70 + c] = v;
          s += v; q += v*v;
        }
        atomicAdd(&sstat[c], s);
        atomicAdd(&sstat[80 + c], q);
      }
    }
  }
  __syncthreads();
  for (int idx = tid; idx < 160; idx += 256) atomicAdd(&hstats[idx], sstat[idx]);
}

// ---------------- BN finalize (hedge): a,b per column ----------------
__global__ void k_bn_fin_hedge(const float* __restrict__ stats,
                               const float* __restrict__ gf, const float* __restrict__ btf,
                               const float* __restrict__ gc, const float* __restrict__ btc,
                               float* __restrict__ ab, float invN){
  int j = threadIdx.x;
  if (j >= 70) return;
  float m = stats[j]*invN;
  float var = stats[80+j]*invN - m*m;
  float gg = (j < 35) ? gf[j] : gc[j-35];
  float bb = (j < 35) ? btf[j] : btc[j-35];
  float a = gg*rsqrtf(var + 1e-5f);
  ab[j] = a; ab[70+j] = bb - m*a;
}

// ---------------- hedge feats + project: heFC = hf @ [W2f_bot|W2c_bot] + [bf2|bc2] ----------------
// GEMM [200K x 35] @ [35 x 128]; KP=36, NC=8 (staggered).
__global__ void k_hedge_feats(const float* __restrict__ tfc, const float* __restrict__ ab,
                              const float* __restrict__ Wf2, const float* __restrict__ bf2,
                              const float* __restrict__ Wc2, const float* __restrict__ bc2,
                              float* __restrict__ heFC){
  __shared__ __align__(16) float As[64*36];
  __shared__ __align__(16) float Ws[128*36];
  int tid = threadIdx.x;
  for (int idx = tid; idx < 128*36; idx += 256){
    int c = idx/36, k = idx - c*36;
    float w = 0.f;
    if (k < 35) w = (c < 64) ? Wf2[(64+k)*64 + c] : Wc2[(64+k)*64 + (c - 64)];
    Ws[idx] = w;
  }
  int rt = tid & 15, ct = tid >> 4;
  float bias[8];
  #pragma unroll
  for (int j = 0; j < 8; ++j){
    int c = ct*8 + ((j + ct) & 7);
    bias[j] = (c < 64) ? bf2[c] : bc2[c - 64];
  }
  for (int tile = blockIdx.x; tile < N_HEDGES_/64; tile += gridDim.x){
    int rbase = tile*64;
    __syncthreads();
    for (int idx = tid; idx < 64*36; idx += 256){
      int r = idx/36, k = idx - r*36;
      float v = 0.f;
      if (k < 35){
        int rg = rbase + r;
        float zf = ab[k]     * tfc[(size_t)rg*70 + k]      + ab[70 + k];
        float zc = ab[35 + k]* tfc[(size_t)rg*70 + 35 + k] + ab[105 + k];
        v = sigm_(zf)*sp_(zc);
      }
      As[idx] = v;
    }
    __syncthreads();
    float acc[4][8] = {};
    for (int kc = 0; kc < 9; ++kc){
      float4 av[4], wv[8];
      #pragma unroll
      for (int i = 0; i < 4; ++i) av[i] = *(const float4*)&As[(rt + 16*i)*36 + kc*4];
      #pragma unroll
      for (int j = 0; j < 8; ++j) wv[j] = *(const float4*)&Ws[(ct*8 + ((j + ct) & 7))*36 + kc*4];
      #pragma unroll
      for (int i = 0; i < 4; ++i)
        #pragma unroll
        for (int j = 0; j < 8; ++j)
          acc[i][j] += av[i].x*wv[j].x + av[i].y*wv[j].y + av[i].z*wv[j].z + av[i].w*wv[j].w;
    }
    #pragma unroll
    for (int i = 0; i < 4; ++i){
      int r = rbase + rt + 16*i;
      #pragma unroll
      for (int j = 0; j < 8; ++j){
        int c = ct*8 + ((j + ct) & 7);
        heFC[(size_t)r*128 + c] = acc[i][j] + bias[j];
      }
    }
  }
}

// ---------------- node projections: nFC = h @ [W2f_top|W2c_top]  (no bias) ----------------
// GEMM [100K x 64] @ [64 x 128]; KP=68, NC=8 (staggered).
__global__ void k_node_lin(const float* __restrict__ h,
                           const float* __restrict__ Wf2, const float* __restrict__ Wc2,
                           float* __restrict__ nFC){
  __shared__ __align__(16) float As[64*68];
  __shared__ __align__(16) float Ws[128*68];
  int tid = threadIdx.x;
  for (int idx = tid; idx < 128*68; idx += 256){
    int c = idx/68, k = idx - c*68;
    float w = 0.f;
    if (k < 64) w = (c < 64) ? Wf2[k*64 + c] : Wc2[k*64 + (c - 64)];
    Ws[idx] = w;
  }
  int rt = tid & 15, ct = tid >> 4;
  const int ntiles = (N_NODES_ + 63)/64;
  for (int tile = blockIdx.x; tile < ntiles; tile += gridDim.x){
    int rbase = tile*64;
    __syncthreads();
    for (int idx = tid; idx < 64*68; idx += 256){
      int r = idx/68, k = idx - r*68;
      int rg = rbase + r;
      As[idx] = (rg < N_NODES_ && k < 64) ? h[(size_t)rg*64 + k] : 0.f;
    }
    __syncthreads();
    float acc[4][8] = {};
    for (int kc = 0; kc < 17; ++kc){
      float4 av[4], wv[8];
      #pragma unroll
      for (int i = 0; i < 4; ++i) av[i] = *(const float4*)&As[(rt + 16*i)*68 + kc*4];
      #pragma unroll
      for (int j = 0; j < 8; ++j) wv[j] = *(const float4*)&Ws[(ct*8 + ((j + ct) & 7))*68 + kc*4];
      #pragma unroll
      for (int i = 0; i < 4; ++i)
        #pragma unroll
        for (int j = 0; j < 8; ++j)
          acc[i][j] += av[i].x*wv[j].x + av[i].y*wv[j].y + av[i].z*wv[j].z + av[i].w*wv[j].w;
    }
    #pragma unroll
    for (int i = 0; i < 4; ++i){
      int r = rbase + rt + 16*i;
      if (r < N_NODES_){
        #pragma unroll
        for (int j = 0; j < 8; ++j){
          int c = ct*8 + ((j + ct) & 7);
          nFC[(size_t)r*128 + c] = acc[i][j];
        }
      }
    }
  }
}

// ---------------- edge kernel: gather + gated act + scatter into node sums ----------------
__global__ void k_edge(const float* __restrict__ nFC, const float* __restrict__ heFC,
                       const int* __restrict__ ni, const int* __restrict__ hi,
                       float* __restrict__ nsum){
  int t = blockIdx.x*256 + threadIdx.x;
  int e = t >> 6; if (e >= E_) return;
  int f = t & 63;
  int n = ni[e], he = hi[e];
  float vF = nFC[(size_t)n*128 + f]      + heFC[(size_t)he*128 + f];
  float vC = nFC[(size_t)n*128 + 64 + f] + heFC[(size_t)he*128 + 64 + f];
  atomicAdd(&nsum[(size_t)n*64 + f], sigm_(vF)*sp_(vC));
}

// ---------------- node BN stats over mean values ----------------
__global__ void k_node_stats(const float* __restrict__ nsum, const float* __restrict__ ninv,
                             float* __restrict__ nstats){
  __shared__ float p1[256], p2[256];
  int f = threadIdx.x & 63, r = threadIdx.x >> 6;
  float s = 0.f, q = 0.f;
  int hi_n = blockIdx.x*1024 + 1024; if (hi_n > N_NODES_) hi_n = N_NODES_;
  for (int n = blockIdx.x*1024 + r; n < hi_n; n += 4){
    float v = nsum[(size_t)n*64+f] * ninv[n];
    s += v; q += v*v;
  }
  p1[threadIdx.x] = s; p2[threadIdx.x] = q;
  __syncthreads();
  if (r == 0){
    s = p1[f] + p1[64+f] + p1[128+f] + p1[192+f];
    q = p2[f] + p2[64+f] + p2[128+f] + p2[192+f];
    atomicAdd(&nstats[f], s);
    atomicAdd(&nstats[64+f], q);
  }
}

__global__ void k_bn_fin_node(const float* __restrict__ stats, const float* __restrict__ g,
                              const float* __restrict__ bt, float* __restrict__ ab, float invN){
  int j = threadIdx.x;
  if (j >= 64) return;
  float m = stats[j]*invN;
  float var = stats[64+j]*invN - m*m;
  float a = g[j]*rsqrtf(var + 1e-5f);
  ab[j] = a; ab[64+j] = bt[j] - m*a;
}

// ---------------- node update: h' = softplus(BN(mean) + h) ----------------
__global__ void k_node_update(const float* __restrict__ nsum, const float* __restrict__ ninv,
                              const float* __restrict__ ab, const float* __restrict__ h,
                              float* __restrict__ hout){
  int t = blockIdx.x*256 + threadIdx.x;
  int n = t >> 6; if (n >= N_NODES_) return;
  int f = t & 63;
  float v = nsum[t] * ninv[n];
  float z = ab[f]*v + ab[64+f] + h[t];
  hout[t] = sp_(z);
}

// ---------------- graph mean + head ----------------
__global__ void k_graph_agg(const float* __restrict__ h, const int* __restrict__ batch,
                            float* __restrict__ gsum){
  int t = blockIdx.x*256 + threadIdx.x;
  int n = t >> 6; if (n >= N_NODES_) return;
  int f = t & 63;
  atomicAdd(&gsum[(size_t)batch[n]*64+f], h[t]);
}

__global__ void k_head(const float* __restrict__ gsum, const int* __restrict__ gcnt,
                       const float* __restrict__ Wl2, const float* __restrict__ bl2,
                       const float* __restrict__ Wo, const float* __restrict__ bo,
                       float* __restrict__ out){
  __shared__ float gm[64];
  __shared__ float red[128];
  int g = blockIdx.x, j = threadIdx.x;
  if (j < 64) gm[j] = gsum[(size_t)g*64+j] / fmaxf((float)gcnt[g], 1.f);
  __syncthreads();
  float u = bl2[j];
  for (int f = 0; f < 64; ++f) u += gm[f]*Wl2[f*128+j];
  red[j] = sp_(u)*Wo[j];
  __syncthreads();
  for (int s = 64; s > 0; s >>= 1){
    if (j < s) red[j] += red[j+s];
    __syncthreads();
  }
  if (j == 0) out[g] = red[0] + bo[0];
}

extern "C" void kernel_launch(void* const* d_in, const int* in_sizes, int n_in,
                              void* d_out, int out_size, void* d_ws, size_t ws_size,
                              hipStream_t stream){
  (void)in_sizes; (void)n_in; (void)out_size; (void)ws_size;
  const float* x      = (const float*)d_in[0];
  const int*   ni     = (const int*)d_in[1];          // hyperedge_index row 0
  const int*   hi     = ni + E_;                      // row 1
  const float* hattr  = (const float*)d_in[2];
  const int*   batch  = (const int*)d_in[3];
  const float* We     = (const float*)d_in[4];
  const float* be     = (const float*)d_in[5];
  const float* Wf1    = (const float*)d_in[6];
  const float* bf1    = (const float*)d_in[7];
  const float* Wc1    = (const float*)d_in[8];
  const float* bc1    = (const float*)d_in[9];
  const float* Wf2    = (const float*)d_in[10];
  const float* bf2    = (const float*)d_in[11];
  const float* Wc2    = (const float*)d_in[12];
  const float* bc2    = (const float*)d_in[13];
  const float* bn_f_g = (const float*)d_in[14];
  const float* bn_f_b = (const float*)d_in[15];
  const float* bn_c_g = (const float*)d_in[16];
  const float* bn_c_b = (const float*)d_in[17];
  const float* bn_o_g = (const float*)d_in[18];
  const float* bn_o_b = (const float*)d_in[19];
  const float* Wl2    = (const float*)d_in[20];
  const float* bl2    = (const float*)d_in[21];
  const float* Wo     = (const float*)d_in[22];
  const float* bo     = (const float*)d_in[23];

  float* ws = (float*)d_ws;
  size_t o = 0;
  float* h0   = ws + o; o += (size_t)N_NODES_*H_;       // 6.4M
  float* h1   = ws + o; o += (size_t)N_NODES_*H_;       // 6.4M
  float* hsum = ws + o; o += (size_t)N_HEDGES_*H_;      // 12.8M
  float* nsum = hsum;                                   // alias: live after hsum consumed
  float* tfc  = ws + o; o += (size_t)N_HEDGES_*70;      // 14.0M
  float* nFC  = tfc;                                    // alias: live after tfc consumed
  float* heFC = ws + o; o += (size_t)N_HEDGES_*128;     // 25.6M
  float* hstats = ws + o; o += 256;
  float* habs   = ws + o; o += 256;
  float* nstats = ws + o; o += 128;
  float* nabs   = ws + o; o += 128;
  float* gsum   = ws + o; o += (size_t)G_*H_;
  float* hinv   = ws + o; o += N_HEDGES_;
  float* ninv   = ws + o; o += N_NODES_;
  int* hcnt = (int*)(ws + o); o += N_HEDGES_;
  int* ndeg = (int*)(ws + o); o += N_NODES_;
  int* gcnt = (int*)(ws + o); o += G_;

  hipMemsetAsync(hcnt, 0, sizeof(int)*N_HEDGES_, stream);
  hipMemsetAsync(ndeg, 0, sizeof(int)*N_NODES_, stream);
  hipMemsetAsync(gcnt, 0, sizeof(int)*G_, stream);
  hipMemsetAsync(gsum, 0, sizeof(float)*G_*H_, stream);

  k_embed<<<768, 256, 0, stream>>>(x, We, be, h0);
  k_counts<<<(E_+255)/256, 256, 0, stream>>>(ni, hi, hcnt, ndeg);
  k_gcnt<<<(N_NODES_+255)/256, 256, 0, stream>>>(batch, gcnt);
  k_inv<<<(N_HEDGES_+255)/256, 256, 0, stream>>>(hcnt, ndeg, hinv, ninv);

  float* hcur = h0;
  float* hnxt = h1;
  for (int l = 0; l < L_; ++l){
    const float* Wf1l = Wf1 + (size_t)l*D_*HE_;
    const float* Wc1l = Wc1 + (size_t)l*D_*HE_;
    const float* Wf2l = Wf2 + (size_t)l*D_*H_;
    const float* Wc2l = Wc2 + (size_t)l*D_*H_;

    hipMemsetAsync(hsum, 0, sizeof(float)*(size_t)N_HEDGES_*H_, stream);
    hipMemsetAsync(hstats, 0, sizeof(float)*160, stream);
    hipMemsetAsync(nstats, 0, sizeof(float)*128, stream);

    k_scatter_hedge<<<E_/4, 256, 0, stream>>>(hcur, ni, hi, hsum);
    k_hedge_mlp1<<<512, 256, 0, stream>>>(hsum, hinv, hattr, Wf1l, bf1 + l*HE_,
                                          Wc1l, bc1 + l*HE_, tfc, hstats);
    k_bn_fin_hedge<<<1, 128, 0, stream>>>(hstats, bn_f_g + l*HE_, bn_f_b + l*HE_,
                                          bn_c_g + l*HE_, bn_c_b + l*HE_, habs,
                                          1.f/(float)N_HEDGES_);
    k_hedge_feats<<<1024, 256, 0, stream>>>(tfc, habs, Wf2l, bf2 + l*H_,
                                            Wc2l, bc2 + l*H_, heFC);
    // hsum fully consumed; zero its lower half as nsum
    hipMemsetAsync(nsum, 0, sizeof(float)*(size_t)N_NODES_*H_, stream);
    k_node_lin<<<768, 256, 0, stream>>>(hcur, Wf2l, Wc2l, nFC);
    k_edge<<<E_/4, 256, 0, stream>>>(nFC, heFC, ni, hi, nsum);
    k_node_stats<<<(N_NODES_+1023)/1024, 256, 0, stream>>>(nsum, ninv, nstats);
    k_bn_fin_node<<<1, 64, 0, stream>>>(nstats, bn_o_g + l*H_, bn_o_b + l*H_, nabs,
                                        1.f/(float)N_NODES_);
    k_node_update<<<(N_NODES_*H_)/256, 256, 0, stream>>>(nsum, ninv, nabs, hcur, hnxt);
    float* t2 = hcur; hcur = hnxt; hnxt = t2;
  }

  k_graph_agg<<<(N_NODES_*H_)/256, 256, 0, stream>>>(hcur, batch, gsum);
  k_head<<<G_, 128, 0, stream>>>(gsum, gcnt, Wl2, bl2, Wo, bo, (float*)d_out);
}